// Round 12
// baseline (29.087 us; speedup 1.0000x reference)
//
#include <hip/hip_runtime.h>

// DiffJPEG fused, v11b: v10 + store-overlap schedule + no VGPR cap + nt stores.
// Strip = 16x64 px per wave: 16 Y blocks (2 passes) + 4 Cb + 4 Cr (1 pass).
// Schedule: loads(all) -> convA -> convB -> yA-pass -> chroma-pass ->
//           store-A (drains under yB) -> yB-pass -> store-B.
// 2 independent waves per 128-thread block; wave-local LDS fences only.

__device__ constexpr float YTAB8[8][8] = {   // = _Y transposed (Y_TABLE)
    {16, 12, 14, 14, 18, 24, 49, 72},
    {11, 12, 13, 17, 22, 35, 64, 92},
    {10, 14, 16, 22, 37, 55, 78, 95},
    {16, 19, 24, 29, 56, 64, 87, 98},
    {24, 26, 40, 51, 68, 81, 103, 112},
    {40, 58, 57, 87, 109, 104, 121, 100},
    {51, 60, 69, 80, 103, 113, 120, 103},
    {61, 55, 56, 62, 77, 92, 101, 99}};

__device__ constexpr float CTAB8[8][8] = {
    {17, 18, 24, 47, 99, 99, 99, 99},
    {18, 21, 26, 66, 99, 99, 99, 99},
    {24, 26, 56, 99, 99, 99, 99, 99},
    {47, 66, 99, 99, 99, 99, 99, 99},
    {99, 99, 99, 99, 99, 99, 99, 99},
    {99, 99, 99, 99, 99, 99, 99, 99},
    {99, 99, 99, 99, 99, 99, 99, 99},
    {99, 99, 99, 99, 99, 99, 99, 99}};

#define C1f 0.9807852804032304f
#define C2f 0.9238795325112867f
#define C3f 0.8314696123025452f
#define C4f 0.7071067811865476f
#define C5f 0.5555702330196022f
#define C6f 0.3826834323650898f
#define C7f 0.1950903220161283f

typedef float vf4 __attribute__((ext_vector_type(4)));

__device__ __forceinline__ void dct8(float y[8]) {
    float e0=y[0]+y[7], e1=y[1]+y[6], e2=y[2]+y[5], e3=y[3]+y[4];
    float o0=y[0]-y[7], o1=y[1]-y[6], o2=y[2]-y[5], o3=y[3]-y[4];
    float t0=e0+e3, t1=e1+e2, d0=e0-e3, d1=e1-e2;
    y[0]=t0+t1; y[4]=(t0-t1)*C4f;
    y[2]=d0*C2f+d1*C6f; y[6]=d0*C6f-d1*C2f;
    y[1]=o0*C1f+o1*C3f+o2*C5f+o3*C7f;
    y[3]=o0*C3f-o1*C7f-o2*C1f-o3*C5f;
    y[5]=o0*C5f-o1*C1f+o2*C7f+o3*C3f;
    y[7]=o0*C7f-o1*C5f+o2*C3f-o3*C1f;
}

__device__ __forceinline__ void idct8(float y[8]) {
    float a=y[4]*C4f, p=y[0]+a, m=y[0]-a;
    float q=y[2]*C2f+y[6]*C6f, w=y[2]*C6f-y[6]*C2f;
    float E0=p+q, E1=m+w, E2=m-w, E3=p-q;
    float O0=y[1]*C1f+y[3]*C3f+y[5]*C5f+y[7]*C7f;
    float O1=y[1]*C3f-y[3]*C7f-y[5]*C1f-y[7]*C5f;
    float O2=y[1]*C5f-y[3]*C1f+y[5]*C7f+y[7]*C3f;
    float O3=y[1]*C7f-y[3]*C5f+y[5]*C3f-y[7]*C1f;
    y[0]=E0+O0; y[7]=E0-O0; y[1]=E1+O1; y[6]=E1-O1;
    y[2]=E2+O2; y[5]=E2-O2; y[3]=E3+O3; y[4]=E3-O3;
}

// 8x8 transpose across the 8 lanes (bits 3..5) holding one block.
__device__ __forceinline__ void transpose8(float y[8]) {
    const int lane = threadIdx.x & 63;
#pragma unroll
    for (int s = 1; s <= 4; s <<= 1) {
        const bool upper = (lane & (s << 3)) != 0;
#pragma unroll
        for (int j = 0; j < 8; ++j) {
            if ((j & s) == 0) {
                float a = y[j], b2 = y[j | s];
                float t = upper ? a : b2;
                t = __shfl_xor(t, s << 3, 64);
                if (upper) y[j] = t; else y[j | s] = t;
            }
        }
    }
}

// wave-synchronous LDS fence (intra-wave producer->consumer ordering only)
__device__ __forceinline__ void wave_lds_fence() {
    __builtin_amdgcn_wave_barrier();
    asm volatile("s_waitcnt lgkmcnt(0)" ::: "memory");
    __builtin_amdgcn_wave_barrier();
}

// diff_round: hw v_fract (period-1 reduction) + hw v_sin/v_cos (revolutions),
// Chebyshev recurrence for harmonics 2..9.
__device__ __forceinline__ float diff_round_f(float x) {
    float f = __builtin_amdgcn_fractf(x);
    float sc = __builtin_amdgcn_sinf(f);
    float c1v = __builtin_amdgcn_cosf(f);
    float twoc = 2.0f * c1v;
    float sp = 0.0f, acc = 0.0f;
    const float coef[9] = {1.0f, -0.5f, 1.0f/3.0f, -0.25f, 0.2f,
                           -1.0f/6.0f, 1.0f/7.0f, -0.125f, 1.0f/9.0f};
#pragma unroll
    for (int n = 0; n < 9; ++n) {
        acc += coef[n] * sc;
        float sn = twoc * sc - sp;
        sp = sc; sc = sn;
    }
    return x - acc * 0.3183098861837907f;
}

__device__ __forceinline__ void jpeg_block(float y[8], const float* qs, int r) {
    dct8(y); transpose8(y); dct8(y);
#pragma unroll
    for (int j = 0; j < 8; ++j) {
        float2 sv = *(const float2*)&qs[2 * (j * 8 + r)];   // ds_read_b64
        y[j] = diff_round_f(y[j] * sv.x) * sv.y;
    }
    idct8(y); transpose8(y); idct8(y);
}

struct Raw { float4 R0, R1, G0, G1, B0, B1; };

#define PLANE ((size_t)512 * 512)

__device__ __forceinline__ Raw issue_load(const float* __restrict__ src,
                                          int py, int px) {
    const float* p = src + (size_t)py * 512 + px;
    Raw L;
    L.R0 = *(const float4*)(p);
    L.R1 = *(const float4*)(p + 4);
    L.G0 = *(const float4*)(p + PLANE);
    L.G1 = *(const float4*)(p + PLANE + 4);
    L.B0 = *(const float4*)(p + 2 * PLANE);
    L.B1 = *(const float4*)(p + 2 * PLANE + 4);
    return L;
}

__device__ __forceinline__ void convert_pool(const Raw& L, float y[8],
                                             float cb[4], float cr[4]) {
    y[0] = 76.245f*L.R0.x + 149.685f*L.G0.x + 29.07f*L.B0.x - 128.0f;
    y[1] = 76.245f*L.R0.y + 149.685f*L.G0.y + 29.07f*L.B0.y - 128.0f;
    y[2] = 76.245f*L.R0.z + 149.685f*L.G0.z + 29.07f*L.B0.z - 128.0f;
    y[3] = 76.245f*L.R0.w + 149.685f*L.G0.w + 29.07f*L.B0.w - 128.0f;
    y[4] = 76.245f*L.R1.x + 149.685f*L.G1.x + 29.07f*L.B1.x - 128.0f;
    y[5] = 76.245f*L.R1.y + 149.685f*L.G1.y + 29.07f*L.B1.y - 128.0f;
    y[6] = 76.245f*L.R1.z + 149.685f*L.G1.z + 29.07f*L.B1.z - 128.0f;
    y[7] = 76.245f*L.R1.w + 149.685f*L.G1.w + 29.07f*L.B1.w - 128.0f;
    float rh0=L.R0.x+L.R0.y, rh1=L.R0.z+L.R0.w, rh2=L.R1.x+L.R1.y, rh3=L.R1.z+L.R1.w;
    float gh0=L.G0.x+L.G0.y, gh1=L.G0.z+L.G0.w, gh2=L.G1.x+L.G1.y, gh3=L.G1.z+L.G1.w;
    float bh0=L.B0.x+L.B0.y, bh1=L.B0.z+L.B0.w, bh2=L.B1.x+L.B1.y, bh3=L.B1.z+L.B1.w;
    const float kbr = -10.75692f, kbg = -21.11808f, kbb = 31.875f;   // Cb * 255/4
    const float krr =  31.875f,   krg = -26.69136f, krb = -5.18364f; // Cr * 255/4
    cb[0]=kbr*rh0+kbg*gh0+kbb*bh0; cb[1]=kbr*rh1+kbg*gh1+kbb*bh1;
    cb[2]=kbr*rh2+kbg*gh2+kbb*bh2; cb[3]=kbr*rh3+kbg*gh3+kbb*bh3;
    cr[0]=krr*rh0+krg*gh0+krb*bh0; cr[1]=krr*rh1+krg*gh1+krb*bh1;
    cr[2]=krr*rh2+krg*gh2+krb*bh2; cr[3]=krr*rh3+krg*gh3+krb*bh3;
#pragma unroll
    for (int k = 0; k < 4; ++k) {   // vertical pair add (rows r, r^1)
        cb[k] += __shfl_xor(cb[k], 8, 64);
        cr[k] += __shfl_xor(cr[k], 8, 64);
    }
}

__device__ __forceinline__ void nt_store4(float* p, float a, float b,
                                          float c, float d) {
    vf4 v = {a, b, c, d};
    __builtin_nontemporal_store(v, (vf4*)p);
}

__device__ __forceinline__ void combine_store(
        const float y[8], const float (*CL)[8][36],
        float* __restrict__ dst, int py, int px, int prow, int b) {
    float4 cb4 = *(const float4*)&CL[0][prow][b * 4];
    float4 cr4 = *(const float4*)&CL[1][prow][b * 4];
    const float cbv[4] = {cb4.x, cb4.y, cb4.z, cb4.w};
    const float crv[4] = {cr4.x, cr4.y, cr4.z, cr4.w};
    float* p = dst + (size_t)py * 512 + px;
    float o[8];
#pragma unroll
    for (int j = 0; j < 8; ++j) {
        float v = (y[j] + 128.0f) + 1.402f * crv[j >> 1];
        o[j] = fminf(fmaxf(v, 0.0f), 255.0f) * (1.0f / 255.0f);
    }
    nt_store4(p,     o[0], o[1], o[2], o[3]);
    nt_store4(p + 4, o[4], o[5], o[6], o[7]);
#pragma unroll
    for (int j = 0; j < 8; ++j) {
        float v = (y[j] + 128.0f) - 0.344136f * cbv[j >> 1] - 0.714136f * crv[j >> 1];
        o[j] = fminf(fmaxf(v, 0.0f), 255.0f) * (1.0f / 255.0f);
    }
    nt_store4(p + PLANE,     o[0], o[1], o[2], o[3]);
    nt_store4(p + PLANE + 4, o[4], o[5], o[6], o[7]);
#pragma unroll
    for (int j = 0; j < 8; ++j) {
        float v = (y[j] + 128.0f) + 1.772f * cbv[j >> 1];
        o[j] = fminf(fmaxf(v, 0.0f), 255.0f) * (1.0f / 255.0f);
    }
    nt_store4(p + 2 * PLANE,     o[0], o[1], o[2], o[3]);
    nt_store4(p + 2 * PLANE + 4, o[4], o[5], o[6], o[7]);
}

__global__ __launch_bounds__(128) void diffjpeg_kernel(
        const float* __restrict__ x, float* __restrict__ out) {
    __shared__ float QS[2][128];
    __shared__ float PLs[2][2][8][36];   // [wave][ch][prow 0..7][pcol 0..31]
    __shared__ float CLs[2][2][8][36];

    const int tid = threadIdx.x;
    {
        int type = tid >> 6;
        int k = tid & 63, u = k >> 3, v = k & 7;
        float t = (type ? CTAB8[u][v] : YTAB8[u][v]) * 0.1f;
        float aa = 0.25f * ((u == 0) ? C4f : 1.0f) * ((v == 0) ? C4f : 1.0f);
        QS[type][2 * k]     = aa / t;
        QS[type][2 * k + 1] = aa * t;
    }
    __syncthreads();   // QS ready (only inter-wave coupling)

    const int wv = tid >> 6;
    const int lane = tid & 63;
    const int r = lane >> 3;
    const int b = lane & 7;

    float (*PL)[8][36] = PLs[wv];
    float (*CL)[8][36] = CLs[wv];

    const int wave_gid = blockIdx.x * 2 + wv;   // 0..4095
    const int img = wave_gid >> 8;              // 256 strips per image
    const int loc = wave_gid & 255;
    const int sy = (loc >> 3) * 16;             // 32 bands
    const int sx = (loc & 7) * 64;              // 8 strip-cols
    const float* src = x + (size_t)img * 3 * PLANE;
    float* dst = out + (size_t)img * 3 * PLANE;

    const int px  = sx + b * 8;
    const int pyA = sy + r;
    const int pyB = sy + 8 + r;

    // ---- P0: all loads issued up front ----
    Raw LA = issue_load(src, pyA, px);
    Raw LB = issue_load(src, pyB, px);

    float yA[8], cbA[4], crA[4];
    convert_pool(LA, yA, cbA, crA);
    if (!(r & 1)) {
        const int prow = r >> 1;            // pass A -> pooled rows 0..3
        *(float4*)&PL[0][prow][b * 4] = make_float4(cbA[0], cbA[1], cbA[2], cbA[3]);
        *(float4*)&PL[1][prow][b * 4] = make_float4(crA[0], crA[1], crA[2], crA[3]);
    }
    float yB[8], cbB[4], crB[4];
    convert_pool(LB, yB, cbB, crB);
    if (!(r & 1)) {
        const int prow = 4 + (r >> 1);      // pass B -> pooled rows 4..7
        *(float4*)&PL[0][prow][b * 4] = make_float4(cbB[0], cbB[1], cbB[2], cbB[3]);
        *(float4*)&PL[1][prow][b * 4] = make_float4(crB[0], crB[1], crB[2], crB[3]);
    }
    wave_lds_fence();   // PL ready

    // ---- P1: yA pass, then chroma pass ----
    jpeg_block(yA, QS[0], r);

    {
        const int ch = b >> 2;              // 0=Cb (b 0..3), 1=Cr (b 4..7)
        const int cblk = b & 3;             // chroma block col 0..3
        float c[8];
        float4 c0 = *(const float4*)&PL[ch][r][cblk * 8];
        float4 c1 = *(const float4*)&PL[ch][r][cblk * 8 + 4];
        c[0]=c0.x; c[1]=c0.y; c[2]=c0.z; c[3]=c0.w;
        c[4]=c1.x; c[5]=c1.y; c[6]=c1.z; c[7]=c1.w;
        jpeg_block(c, QS[1], r);
        *(float4*)&CL[ch][r][cblk * 8]     = make_float4(c[0], c[1], c[2], c[3]);
        *(float4*)&CL[ch][r][cblk * 8 + 4] = make_float4(c[4], c[5], c[6], c[7]);
    }
    wave_lds_fence();   // CL ready

    // ---- P2: store A early (drains under yB pass), then yB, store B ----
    combine_store(yA, CL, dst, pyA, px, (r >> 1), b);

    jpeg_block(yB, QS[0], r);

    combine_store(yB, CL, dst, pyB, px, 4 + (r >> 1), b);
}

extern "C" void kernel_launch(void* const* d_in, const int* in_sizes, int n_in,
                              void* d_out, int out_size, void* d_ws, size_t ws_size,
                              hipStream_t stream) {
    const float* x = (const float*)d_in[0];
    float* out = (float*)d_out;
    dim3 grid(2048);     // 2 waves/block x 1 strip(16x64)/wave = 4096 strips
    dim3 block(128);
    diffjpeg_kernel<<<grid, block, 0, stream>>>(x, out);
}

// Round 13
// 23.780 us; speedup vs baseline: 1.2231x; 1.2231x over previous
//
#include <hip/hip_runtime.h>

// DiffJPEG fused, v12: v10 + early store-A (drains under yB pass).
// Strip = 16x64 px per wave: 16 Y blocks (2 passes) + 4 Cb + 4 Cr (1 pass).
// Schedule: loads(all) -> convA -> convB -> yA-pass -> chroma-pass ->
//           store-A -> yB-pass (store-A drains underneath) -> store-B.
// Normal float4 stores (L2 write-coalescing); __launch_bounds__(128,4).
// 2 independent waves per 128-thread block; wave-local LDS fences only.

__device__ constexpr float YTAB8[8][8] = {   // = _Y transposed (Y_TABLE)
    {16, 12, 14, 14, 18, 24, 49, 72},
    {11, 12, 13, 17, 22, 35, 64, 92},
    {10, 14, 16, 22, 37, 55, 78, 95},
    {16, 19, 24, 29, 56, 64, 87, 98},
    {24, 26, 40, 51, 68, 81, 103, 112},
    {40, 58, 57, 87, 109, 104, 121, 100},
    {51, 60, 69, 80, 103, 113, 120, 103},
    {61, 55, 56, 62, 77, 92, 101, 99}};

__device__ constexpr float CTAB8[8][8] = {
    {17, 18, 24, 47, 99, 99, 99, 99},
    {18, 21, 26, 66, 99, 99, 99, 99},
    {24, 26, 56, 99, 99, 99, 99, 99},
    {47, 66, 99, 99, 99, 99, 99, 99},
    {99, 99, 99, 99, 99, 99, 99, 99},
    {99, 99, 99, 99, 99, 99, 99, 99},
    {99, 99, 99, 99, 99, 99, 99, 99},
    {99, 99, 99, 99, 99, 99, 99, 99}};

#define C1f 0.9807852804032304f
#define C2f 0.9238795325112867f
#define C3f 0.8314696123025452f
#define C4f 0.7071067811865476f
#define C5f 0.5555702330196022f
#define C6f 0.3826834323650898f
#define C7f 0.1950903220161283f

__device__ __forceinline__ void dct8(float y[8]) {
    float e0=y[0]+y[7], e1=y[1]+y[6], e2=y[2]+y[5], e3=y[3]+y[4];
    float o0=y[0]-y[7], o1=y[1]-y[6], o2=y[2]-y[5], o3=y[3]-y[4];
    float t0=e0+e3, t1=e1+e2, d0=e0-e3, d1=e1-e2;
    y[0]=t0+t1; y[4]=(t0-t1)*C4f;
    y[2]=d0*C2f+d1*C6f; y[6]=d0*C6f-d1*C2f;
    y[1]=o0*C1f+o1*C3f+o2*C5f+o3*C7f;
    y[3]=o0*C3f-o1*C7f-o2*C1f-o3*C5f;
    y[5]=o0*C5f-o1*C1f+o2*C7f+o3*C3f;
    y[7]=o0*C7f-o1*C5f+o2*C3f-o3*C1f;
}

__device__ __forceinline__ void idct8(float y[8]) {
    float a=y[4]*C4f, p=y[0]+a, m=y[0]-a;
    float q=y[2]*C2f+y[6]*C6f, w=y[2]*C6f-y[6]*C2f;
    float E0=p+q, E1=m+w, E2=m-w, E3=p-q;
    float O0=y[1]*C1f+y[3]*C3f+y[5]*C5f+y[7]*C7f;
    float O1=y[1]*C3f-y[3]*C7f-y[5]*C1f-y[7]*C5f;
    float O2=y[1]*C5f-y[3]*C1f+y[5]*C7f+y[7]*C3f;
    float O3=y[1]*C7f-y[3]*C5f+y[5]*C3f-y[7]*C1f;
    y[0]=E0+O0; y[7]=E0-O0; y[1]=E1+O1; y[6]=E1-O1;
    y[2]=E2+O2; y[5]=E2-O2; y[3]=E3+O3; y[4]=E3-O3;
}

// 8x8 transpose across the 8 lanes (bits 3..5) holding one block.
__device__ __forceinline__ void transpose8(float y[8]) {
    const int lane = threadIdx.x & 63;
#pragma unroll
    for (int s = 1; s <= 4; s <<= 1) {
        const bool upper = (lane & (s << 3)) != 0;
#pragma unroll
        for (int j = 0; j < 8; ++j) {
            if ((j & s) == 0) {
                float a = y[j], b2 = y[j | s];
                float t = upper ? a : b2;
                t = __shfl_xor(t, s << 3, 64);
                if (upper) y[j] = t; else y[j | s] = t;
            }
        }
    }
}

// wave-synchronous LDS fence (intra-wave producer->consumer ordering only)
__device__ __forceinline__ void wave_lds_fence() {
    __builtin_amdgcn_wave_barrier();
    asm volatile("s_waitcnt lgkmcnt(0)" ::: "memory");
    __builtin_amdgcn_wave_barrier();
}

// diff_round: hw v_fract (period-1 reduction) + hw v_sin/v_cos (revolutions),
// Chebyshev recurrence for harmonics 2..9.
__device__ __forceinline__ float diff_round_f(float x) {
    float f = __builtin_amdgcn_fractf(x);
    float sc = __builtin_amdgcn_sinf(f);
    float c1v = __builtin_amdgcn_cosf(f);
    float twoc = 2.0f * c1v;
    float sp = 0.0f, acc = 0.0f;
    const float coef[9] = {1.0f, -0.5f, 1.0f/3.0f, -0.25f, 0.2f,
                           -1.0f/6.0f, 1.0f/7.0f, -0.125f, 1.0f/9.0f};
#pragma unroll
    for (int n = 0; n < 9; ++n) {
        acc += coef[n] * sc;
        float sn = twoc * sc - sp;
        sp = sc; sc = sn;
    }
    return x - acc * 0.3183098861837907f;
}

__device__ __forceinline__ void jpeg_block(float y[8], const float* qs, int r) {
    dct8(y); transpose8(y); dct8(y);
#pragma unroll
    for (int j = 0; j < 8; ++j) {
        float2 sv = *(const float2*)&qs[2 * (j * 8 + r)];   // ds_read_b64
        y[j] = diff_round_f(y[j] * sv.x) * sv.y;
    }
    idct8(y); transpose8(y); idct8(y);
}

struct Raw { float4 R0, R1, G0, G1, B0, B1; };

#define PLANE ((size_t)512 * 512)

__device__ __forceinline__ Raw issue_load(const float* __restrict__ src,
                                          int py, int px) {
    const float* p = src + (size_t)py * 512 + px;
    Raw L;
    L.R0 = *(const float4*)(p);
    L.R1 = *(const float4*)(p + 4);
    L.G0 = *(const float4*)(p + PLANE);
    L.G1 = *(const float4*)(p + PLANE + 4);
    L.B0 = *(const float4*)(p + 2 * PLANE);
    L.B1 = *(const float4*)(p + 2 * PLANE + 4);
    return L;
}

__device__ __forceinline__ void convert_pool(const Raw& L, float y[8],
                                             float cb[4], float cr[4]) {
    y[0] = 76.245f*L.R0.x + 149.685f*L.G0.x + 29.07f*L.B0.x - 128.0f;
    y[1] = 76.245f*L.R0.y + 149.685f*L.G0.y + 29.07f*L.B0.y - 128.0f;
    y[2] = 76.245f*L.R0.z + 149.685f*L.G0.z + 29.07f*L.B0.z - 128.0f;
    y[3] = 76.245f*L.R0.w + 149.685f*L.G0.w + 29.07f*L.B0.w - 128.0f;
    y[4] = 76.245f*L.R1.x + 149.685f*L.G1.x + 29.07f*L.B1.x - 128.0f;
    y[5] = 76.245f*L.R1.y + 149.685f*L.G1.y + 29.07f*L.B1.y - 128.0f;
    y[6] = 76.245f*L.R1.z + 149.685f*L.G1.z + 29.07f*L.B1.z - 128.0f;
    y[7] = 76.245f*L.R1.w + 149.685f*L.G1.w + 29.07f*L.B1.w - 128.0f;
    float rh0=L.R0.x+L.R0.y, rh1=L.R0.z+L.R0.w, rh2=L.R1.x+L.R1.y, rh3=L.R1.z+L.R1.w;
    float gh0=L.G0.x+L.G0.y, gh1=L.G0.z+L.G0.w, gh2=L.G1.x+L.G1.y, gh3=L.G1.z+L.G1.w;
    float bh0=L.B0.x+L.B0.y, bh1=L.B0.z+L.B0.w, bh2=L.B1.x+L.B1.y, bh3=L.B1.z+L.B1.w;
    const float kbr = -10.75692f, kbg = -21.11808f, kbb = 31.875f;   // Cb * 255/4
    const float krr =  31.875f,   krg = -26.69136f, krb = -5.18364f; // Cr * 255/4
    cb[0]=kbr*rh0+kbg*gh0+kbb*bh0; cb[1]=kbr*rh1+kbg*gh1+kbb*bh1;
    cb[2]=kbr*rh2+kbg*gh2+kbb*bh2; cb[3]=kbr*rh3+kbg*gh3+kbb*bh3;
    cr[0]=krr*rh0+krg*gh0+krb*bh0; cr[1]=krr*rh1+krg*gh1+krb*bh1;
    cr[2]=krr*rh2+krg*gh2+krb*bh2; cr[3]=krr*rh3+krg*gh3+krb*bh3;
#pragma unroll
    for (int k = 0; k < 4; ++k) {   // vertical pair add (rows r, r^1)
        cb[k] += __shfl_xor(cb[k], 8, 64);
        cr[k] += __shfl_xor(cr[k], 8, 64);
    }
}

__device__ __forceinline__ void combine_store(
        const float y[8], const float (*CL)[8][36],
        float* __restrict__ dst, int py, int px, int prow, int b) {
    float4 cb4 = *(const float4*)&CL[0][prow][b * 4];
    float4 cr4 = *(const float4*)&CL[1][prow][b * 4];
    const float cbv[4] = {cb4.x, cb4.y, cb4.z, cb4.w};
    const float crv[4] = {cr4.x, cr4.y, cr4.z, cr4.w};
    float* p = dst + (size_t)py * 512 + px;
    float o[8];
#pragma unroll
    for (int j = 0; j < 8; ++j) {
        float v = (y[j] + 128.0f) + 1.402f * crv[j >> 1];
        o[j] = fminf(fmaxf(v, 0.0f), 255.0f) * (1.0f / 255.0f);
    }
    *(float4*)(p)     = make_float4(o[0], o[1], o[2], o[3]);
    *(float4*)(p + 4) = make_float4(o[4], o[5], o[6], o[7]);
#pragma unroll
    for (int j = 0; j < 8; ++j) {
        float v = (y[j] + 128.0f) - 0.344136f * cbv[j >> 1] - 0.714136f * crv[j >> 1];
        o[j] = fminf(fmaxf(v, 0.0f), 255.0f) * (1.0f / 255.0f);
    }
    *(float4*)(p + PLANE)     = make_float4(o[0], o[1], o[2], o[3]);
    *(float4*)(p + PLANE + 4) = make_float4(o[4], o[5], o[6], o[7]);
#pragma unroll
    for (int j = 0; j < 8; ++j) {
        float v = (y[j] + 128.0f) + 1.772f * cbv[j >> 1];
        o[j] = fminf(fmaxf(v, 0.0f), 255.0f) * (1.0f / 255.0f);
    }
    *(float4*)(p + 2 * PLANE)     = make_float4(o[0], o[1], o[2], o[3]);
    *(float4*)(p + 2 * PLANE + 4) = make_float4(o[4], o[5], o[6], o[7]);
}

__global__ __launch_bounds__(128, 4) void diffjpeg_kernel(
        const float* __restrict__ x, float* __restrict__ out) {
    __shared__ float QS[2][128];
    __shared__ float PLs[2][2][8][36];   // [wave][ch][prow 0..7][pcol 0..31]
    __shared__ float CLs[2][2][8][36];

    const int tid = threadIdx.x;
    {
        int type = tid >> 6;
        int k = tid & 63, u = k >> 3, v = k & 7;
        float t = (type ? CTAB8[u][v] : YTAB8[u][v]) * 0.1f;
        float aa = 0.25f * ((u == 0) ? C4f : 1.0f) * ((v == 0) ? C4f : 1.0f);
        QS[type][2 * k]     = aa / t;
        QS[type][2 * k + 1] = aa * t;
    }
    __syncthreads();   // QS ready (only inter-wave coupling)

    const int wv = tid >> 6;
    const int lane = tid & 63;
    const int r = lane >> 3;
    const int b = lane & 7;

    float (*PL)[8][36] = PLs[wv];
    float (*CL)[8][36] = CLs[wv];

    const int wave_gid = blockIdx.x * 2 + wv;   // 0..4095
    const int img = wave_gid >> 8;              // 256 strips per image
    const int loc = wave_gid & 255;
    const int sy = (loc >> 3) * 16;             // 32 bands
    const int sx = (loc & 7) * 64;              // 8 strip-cols
    const float* src = x + (size_t)img * 3 * PLANE;
    float* dst = out + (size_t)img * 3 * PLANE;

    const int px  = sx + b * 8;
    const int pyA = sy + r;
    const int pyB = sy + 8 + r;

    // ---- P0: all loads issued up front ----
    Raw LA = issue_load(src, pyA, px);
    Raw LB = issue_load(src, pyB, px);

    float yA[8], cbA[4], crA[4];
    convert_pool(LA, yA, cbA, crA);
    if (!(r & 1)) {
        const int prow = r >> 1;            // pass A -> pooled rows 0..3
        *(float4*)&PL[0][prow][b * 4] = make_float4(cbA[0], cbA[1], cbA[2], cbA[3]);
        *(float4*)&PL[1][prow][b * 4] = make_float4(crA[0], crA[1], crA[2], crA[3]);
    }
    float yB[8], cbB[4], crB[4];
    convert_pool(LB, yB, cbB, crB);
    if (!(r & 1)) {
        const int prow = 4 + (r >> 1);      // pass B -> pooled rows 4..7
        *(float4*)&PL[0][prow][b * 4] = make_float4(cbB[0], cbB[1], cbB[2], cbB[3]);
        *(float4*)&PL[1][prow][b * 4] = make_float4(crB[0], crB[1], crB[2], crB[3]);
    }
    wave_lds_fence();   // PL ready

    // ---- P1: yA pass, then chroma pass ----
    jpeg_block(yA, QS[0], r);

    {
        const int ch = b >> 2;              // 0=Cb (b 0..3), 1=Cr (b 4..7)
        const int cblk = b & 3;             // chroma block col 0..3
        float c[8];
        float4 c0 = *(const float4*)&PL[ch][r][cblk * 8];
        float4 c1 = *(const float4*)&PL[ch][r][cblk * 8 + 4];
        c[0]=c0.x; c[1]=c0.y; c[2]=c0.z; c[3]=c0.w;
        c[4]=c1.x; c[5]=c1.y; c[6]=c1.z; c[7]=c1.w;
        jpeg_block(c, QS[1], r);
        *(float4*)&CL[ch][r][cblk * 8]     = make_float4(c[0], c[1], c[2], c[3]);
        *(float4*)&CL[ch][r][cblk * 8 + 4] = make_float4(c[4], c[5], c[6], c[7]);
    }
    wave_lds_fence();   // CL ready

    // ---- P2: store A early (drains under yB pass), then yB, store B ----
    combine_store(yA, CL, dst, pyA, px, (r >> 1), b);

    jpeg_block(yB, QS[0], r);

    combine_store(yB, CL, dst, pyB, px, 4 + (r >> 1), b);
}

extern "C" void kernel_launch(void* const* d_in, const int* in_sizes, int n_in,
                              void* d_out, int out_size, void* d_ws, size_t ws_size,
                              hipStream_t stream) {
    const float* x = (const float*)d_in[0];
    float* out = (float*)d_out;
    dim3 grid(2048);     // 2 waves/block x 1 strip(16x64)/wave = 4096 strips
    dim3 block(128);
    diffjpeg_kernel<<<grid, block, 0, stream>>>(x, out);
}